// Round 3
// baseline (3823.780 us; speedup 1.0000x reference)
//
#include <hip/hip_runtime.h>

typedef _Float16 half_t;
typedef _Float16 half8 __attribute__((ext_vector_type(8)));
typedef _Float16 half4 __attribute__((ext_vector_type(4)));
typedef float float4v __attribute__((ext_vector_type(4)));

constexpr int NB = 64;    // batch
constexpr int NT = 50;    // steps
constexpr int NS = 256;   // state dim
constexpr int NA = 64;    // action dim
constexpr int NH = 256;   // hypernet hidden

constexpr float LO_SCALE = 2048.0f;   // keep lo words out of fp16 denormal range
constexpr float LO_INV   = 1.0f / 2048.0f;

// ---------------- preprocess kernels ----------------

__global__ void k_zero(unsigned* __restrict__ p, int n) {
  int idx = blockIdx.x * 256 + threadIdx.x;
  if (idx < n) p[idx] = 0u;
}

// HA/HB[t][b][h] = tanh((ctx[b]+t/50)*W1[h]+b1[h]) in fp32
__global__ void k_hahb(const float* __restrict__ ctx, const float* __restrict__ W1a,
                       const float* __restrict__ b1a, const float* __restrict__ W1b,
                       const float* __restrict__ b1b, float* __restrict__ HA,
                       float* __restrict__ HB) {
  int tb = blockIdx.x;              // t*NB + b
  int t = tb / NB, b = tb % NB;
  int h = threadIdx.x;
  float z = ctx[b] + (float)t / 50.0f;
  HA[(size_t)tb * NH + h] = tanhf(z * W1a[h] + b1a[h]);
  HB[(size_t)tb * NH + h] = tanhf(z * W1b[h] + b1b[h]);
}

// V[t][b][i] = sum_j b2b[i*NA+j] * us[b][t][j]   (fp32)
__global__ void k_v(const float* __restrict__ b2b, const float* __restrict__ us,
                    float* __restrict__ V) {
  int tb = blockIdx.x;
  int t = tb / NB, b = tb % NB;
  int i = threadIdx.x;
  __shared__ float ush[NA];
  if (i < NA) ush[i] = us[((size_t)b * NT + t) * NA + i];
  __syncthreads();
  const float* row = b2b + (size_t)i * NA;
  float s = 0.f;
#pragma unroll 8
  for (int j = 0; j < NA; ++j) s += row[j] * ush[j];
  V[(size_t)tb * NS + i] = s;
}

// W2a permute+split: [h][i*NS+k] fp32 -> Wah/Wal [i][h][k] fp16 hi / lo*2048
__global__ void k_perma(const float* __restrict__ W2a, half_t* __restrict__ Wah,
                        half_t* __restrict__ Wal) {
  int i = blockIdx.x;
  int kq = (threadIdx.x & 63) * 4;   // k-quad base
  int hs = threadIdx.x >> 6;         // 0..3
  for (int h0 = 0; h0 < NS; h0 += 4) {
    int h = h0 + hs;
    float4v v = *(const float4v*)(W2a + (size_t)h * (NS * NS) + (size_t)i * NS + kq);
    half4 oh, ol;
#pragma unroll
    for (int r = 0; r < 4; ++r) {
      half_t hi = (half_t)v[r];
      oh[r] = hi;
      ol[r] = (half_t)((v[r] - (float)hi) * LO_SCALE);
    }
    *(half4*)(Wah + ((size_t)i * NS + h) * NS + kq) = oh;
    *(half4*)(Wal + ((size_t)i * NS + h) * NS + kq) = ol;
  }
}

// W2b permute+split: [h][i*NA+j] fp32 -> [i][h][j] fp16 hi/lo
__global__ void k_permb(const float* __restrict__ W2b, half_t* __restrict__ Wbh,
                        half_t* __restrict__ Wbl) {
  int i = blockIdx.x;
  int jq = (threadIdx.x & 15) * 4;
  int hh = threadIdx.x >> 4;
  for (int h0 = 0; h0 < NH; h0 += 16) {
    int h = h0 + hh;
    float4v v = *(const float4v*)(W2b + (size_t)h * (NS * NA) + (size_t)i * NA + jq);
    half4 oh, ol;
#pragma unroll
    for (int r = 0; r < 4; ++r) {
      half_t hi = (half_t)v[r];
      oh[r] = hi;
      ol[r] = (half_t)((v[r] - (float)hi) * LO_SCALE);
    }
    *(half4*)(Wbh + ((size_t)i * NH + h) * NA + jq) = oh;
    *(half4*)(Wbl + ((size_t)i * NH + h) * NA + jq) = ol;
  }
}

// us [b][t][j] fp32 -> Uh/Ul [t][b][j] fp16
__global__ void k_u(const float* __restrict__ us, half_t* __restrict__ Uh,
                    half_t* __restrict__ Ul) {
  int t = blockIdx.x, tid = threadIdx.x;
  for (int r = 0; r < 16; ++r) {
    int idx = r * 256 + tid;       // 0..4095
    int b = idx >> 6, j = idx & 63;
    float u = us[((size_t)b * NT + t) * NA + j];
    half_t hi = (half_t)u;
    Uh[((size_t)t * NB + b) * NA + j] = hi;
    Ul[((size_t)t * NB + b) * NA + j] = (half_t)((u - (float)hi) * LO_SCALE);
  }
}

// x0 fp32 [b][k] -> Xf (fp32) + Xh/Xl fp16, parity-0 buffers
__global__ void k_x0(const float* __restrict__ x0, float* __restrict__ Xf,
                     half_t* __restrict__ Xh, half_t* __restrict__ Xl) {
  size_t idx = (size_t)blockIdx.x * 256 + threadIdx.x;
  float x = x0[idx];
  half_t hi = (half_t)x;
  Xf[idx] = x;
  Xh[idx] = hi;
  Xl[idx] = (half_t)((x - (float)hi) * LO_SCALE);
}

// ---------------- per-step kernel ----------------
// grid = 512: block (i = blk>>1, h-half = blk&1), 256 threads = 4 waves.
// Each wave owns 32 h-rows (2 m-tiles). 8 waves per i (across 2 wgs) combine
// into Y[t][i][b] via device-scope atomicAdd; 8th wave (atomic counter) finalizes.
template <bool PRE>
__launch_bounds__(256, 2)
__global__ void k_step(int t, const float* __restrict__ W2a, const float* __restrict__ b2a,
                       const half_t* __restrict__ Wah, const half_t* __restrict__ Wal,
                       const half_t* __restrict__ Wbh, const half_t* __restrict__ Wbl,
                       const half_t* __restrict__ Uh, const half_t* __restrict__ Ul,
                       const float* __restrict__ HA, const float* __restrict__ HB,
                       const float* __restrict__ V, float* __restrict__ Xf,
                       half_t* __restrict__ Xh, half_t* __restrict__ Xl,
                       float* __restrict__ Y, unsigned* __restrict__ cnt,
                       float* __restrict__ out) {
  __shared__ half_t Wlds[128 * 256];          // 64 KiB static: W-hi half-slice

  const int tid = threadIdx.x;
  const int i  = blockIdx.x >> 1;
  const int hh = blockIdx.x & 1;
  const int lane = tid & 63, wv = tid >> 6;
  const int l15 = lane & 15, quad = lane >> 4;

  const float*  Xfc = Xf + (size_t)(t & 1) * (NB * NS);
  const half_t* Xhc = Xh + (size_t)(t & 1) * (NB * NS);
  const half_t* Xlc = Xl + (size_t)(t & 1) * (NB * NS);

  // --- stage W-hi half-slice into LDS, 16B-chunk XOR swizzle: chunk c -> c^(row&7)
  for (int r = 0; r < 16; ++r) {
    int m = r * 256 + tid;          // chunk id 0..4095
    int row = m >> 5, c = m & 31;   // row 0..127, chunk 0..31
    half8 v;
    if (PRE) {
      v = *(const half8*)(Wah + (((size_t)i * NS) + hh * 128 + row) * NS + c * 8);
    } else {
      const float* src = W2a + (size_t)(hh * 128 + row) * (NS * NS) + (size_t)i * NS + c * 8;
      float4v w0 = *(const float4v*)(src);
      float4v w1 = *(const float4v*)(src + 4);
#pragma unroll
      for (int r4 = 0; r4 < 4; ++r4) { v[r4] = (half_t)w0[r4]; v[r4 + 4] = (half_t)w1[r4]; }
    }
    *(half8*)(Wlds + row * 256 + ((c ^ (row & 7)) * 8)) = v;
  }
  __syncthreads();

  float4v accA[2][4], accC[2][4], accU[2][4], accUc[2][4];
#pragma unroll
  for (int mt = 0; mt < 2; ++mt)
#pragma unroll
    for (int nt = 0; nt < 4; ++nt) {
      accA[mt][nt] = (float4v){0.f, 0.f, 0.f, 0.f};
      accC[mt][nt] = (float4v){0.f, 0.f, 0.f, 0.f};
      accU[mt][nt] = (float4v){0.f, 0.f, 0.f, 0.f};
      accUc[mt][nt] = (float4v){0.f, 0.f, 0.f, 0.f};
    }

  // --- A-path: G[h,b] = W2a_i[h,:].x[b,:]  (hi.hi -> accA; hi.lo + lo.hi -> accC)
#pragma unroll
  for (int kb = 0; kb < 8; ++kb) {
    const int ko = kb * 32 + quad * 8;
    half8 bhi[4], blo[4];
#pragma unroll
    for (int nt = 0; nt < 4; ++nt) {
      int b = nt * 16 + l15;
      bhi[nt] = *(const half8*)(Xhc + b * NS + ko);
      blo[nt] = *(const half8*)(Xlc + b * NS + ko);
    }
#pragma unroll
    for (int mt = 0; mt < 2; ++mt) {
      const int hloc = (wv * 2 + mt) * 16 + l15;      // 0..127
      const int kc = kb * 4 + quad;
      half8 ahi = *(const half8*)(Wlds + hloc * 256 + ((kc ^ (hloc & 7)) * 8));
      half8 alo;
      if (PRE) {
        alo = *(const half8*)(Wal + (((size_t)i * NS) + hh * 128 + hloc) * NS + ko);
      } else {
        const float* src = W2a + (size_t)(hh * 128 + hloc) * (NS * NS) + (size_t)i * NS + ko;
        float4v w0 = *(const float4v*)(src);
        float4v w1 = *(const float4v*)(src + 4);
#pragma unroll
        for (int r4 = 0; r4 < 4; ++r4) {
          half_t h0v = (half_t)w0[r4];
          half_t h1v = (half_t)w1[r4];
          alo[r4]     = (half_t)((w0[r4] - (float)h0v) * LO_SCALE);
          alo[r4 + 4] = (half_t)((w1[r4] - (float)h1v) * LO_SCALE);
        }
      }
#pragma unroll
      for (int nt = 0; nt < 4; ++nt) {
        accA[mt][nt] = __builtin_amdgcn_mfma_f32_16x16x32_f16(ahi, bhi[nt], accA[mt][nt], 0, 0, 0);
        accC[mt][nt] = __builtin_amdgcn_mfma_f32_16x16x32_f16(ahi, blo[nt], accC[mt][nt], 0, 0, 0);
        accC[mt][nt] = __builtin_amdgcn_mfma_f32_16x16x32_f16(alo, bhi[nt], accC[mt][nt], 0, 0, 0);
      }
    }
  }

  // --- u-path: Gb[h,b] = W2b_i[h,:].u_t[b,:]
#pragma unroll
  for (int kb = 0; kb < 2; ++kb) {
    const int jo = kb * 32 + quad * 8;
    half8 buh[4], bul[4];
#pragma unroll
    for (int nt = 0; nt < 4; ++nt) {
      int b = nt * 16 + l15;
      buh[nt] = *(const half8*)(Uh + ((size_t)t * NB + b) * NA + jo);
      bul[nt] = *(const half8*)(Ul + ((size_t)t * NB + b) * NA + jo);
    }
#pragma unroll
    for (int mt = 0; mt < 2; ++mt) {
      const int hg = hh * 128 + (wv * 2 + mt) * 16 + l15;
      const size_t wb = ((size_t)i * NH + hg) * NA + jo;
      half8 auh = *(const half8*)(Wbh + wb);
      half8 aul = *(const half8*)(Wbl + wb);
#pragma unroll
      for (int nt = 0; nt < 4; ++nt) {
        accU[mt][nt]  = __builtin_amdgcn_mfma_f32_16x16x32_f16(auh, buh[nt], accU[mt][nt], 0, 0, 0);
        accUc[mt][nt] = __builtin_amdgcn_mfma_f32_16x16x32_f16(auh, bul[nt], accUc[mt][nt], 0, 0, 0);
        accUc[mt][nt] = __builtin_amdgcn_mfma_f32_16x16x32_f16(aul, buh[nt], accUc[mt][nt], 0, 0, 0);
      }
    }
  }

  // --- ha/hb-weighted reduction over this wave's 32 h-rows
  float part[4] = {0.f, 0.f, 0.f, 0.f};
#pragma unroll
  for (int mt = 0; mt < 2; ++mt) {
    int hg = hh * 128 + (wv * 2 + mt) * 16 + quad * 4;
#pragma unroll
    for (int nt = 0; nt < 4; ++nt) {
      int b = nt * 16 + l15;
      float4v ha4 = *(const float4v*)(HA + ((size_t)t * NB + b) * NH + hg);
      float4v hb4 = *(const float4v*)(HB + ((size_t)t * NB + b) * NH + hg);
#pragma unroll
      for (int r = 0; r < 4; ++r) {
        float ga = accA[mt][nt][r] + accC[mt][nt][r] * LO_INV;
        float gb = accU[mt][nt][r] + accUc[mt][nt][r] * LO_INV;
        part[nt] += ha4[r] * ga + hb4[r] * gb;
      }
    }
  }
#pragma unroll
  for (int nt = 0; nt < 4; ++nt) {
    part[nt] += __shfl_xor(part[nt], 16);
    part[nt] += __shfl_xor(part[nt], 32);
  }

  float* Yrow = Y + ((size_t)t * NS + i) * NB;
  if (quad == 0) {
#pragma unroll
    for (int nt = 0; nt < 4; ++nt) atomicAdd(&Yrow[nt * 16 + l15], part[nt]);
  }

  // --- bias_a partial: b2a_i . x_t (fp32, hh==0 wgs only; wave wv covers k quarter)
  if (hh == 0) {
    float bp = 0.f;
    const float* w  = b2a + (size_t)i * NS + wv * 64;
    const float* xr = Xfc + (size_t)lane * NS + wv * 64;
#pragma unroll
    for (int kq = 0; kq < 16; ++kq) {
      float4v wv4 = *(const float4v*)(w + kq * 4);
      float4v xv4 = *(const float4v*)(xr + kq * 4);
      bp += wv4[0] * xv4[0] + wv4[1] * xv4[1] + wv4[2] * xv4[2] + wv4[3] * xv4[3];
    }
    atomicAdd(&Yrow[lane], bp);
  }

  // --- per-wave completion signal; 8th wave for this i finalizes
  __threadfence();
  int old = 0;
  if (lane == 0) old = (int)atomicAdd(&cnt[t * NS + i], 1u);
  old = __shfl(old, 0);
  if (old == 7) {
    int b = lane;
    float y = atomicAdd(&Yrow[b], 0.0f);     // coherent read
    float xf = y + V[((size_t)t * NB + b) * NS + i];
    out[((size_t)b * NT + t) * NS + i] = xf;
    size_t nxt = (size_t)((t + 1) & 1) * (NB * NS) + (size_t)b * NS + i;
    half_t hi = (half_t)xf;
    Xf[nxt] = xf;
    Xh[nxt] = hi;
    Xl[nxt] = (half_t)((xf - (float)hi) * LO_SCALE);
  }
}

// ---------------- launch ----------------

extern "C" void kernel_launch(void* const* d_in, const int* in_sizes, int n_in,
                              void* d_out, int out_size, void* d_ws, size_t ws_size,
                              hipStream_t stream) {
  const float* x0  = (const float*)d_in[0];
  const float* ctx = (const float*)d_in[1];
  const float* us  = (const float*)d_in[2];
  const float* W1a = (const float*)d_in[3];
  const float* b1a = (const float*)d_in[4];
  const float* W2a = (const float*)d_in[5];
  const float* b2a = (const float*)d_in[6];
  const float* W1b = (const float*)d_in[7];
  const float* b1b = (const float*)d_in[8];
  const float* W2b = (const float*)d_in[9];
  const float* b2b = (const float*)d_in[10];
  float* out = (float*)d_out;

  // workspace layout (PRE includes Wah/Wal, 67 MB; fallback streams from fp32 W2a)
  const size_t szWa  = (size_t)NS * NS * NS * 2;      // 33,554,432 each
  const size_t szWb  = (size_t)NS * NH * NA * 2;      //  8,388,608 each
  const size_t szU   = (size_t)NT * NB * NA * 2;      //    409,600 each
  const size_t szH   = (size_t)NT * NB * NH * 4;      //  3,276,800 each
  const size_t szV   = (size_t)NT * NB * NS * 4;      //  3,276,800
  const size_t szXf  = (size_t)2 * NB * NS * 4;       //    131,072
  const size_t szXh  = (size_t)2 * NB * NS * 2;       //     65,536 each
  const size_t szY   = (size_t)NT * NS * NB * 4;      //  3,276,800
  const size_t szCnt = (size_t)NT * NS * 4;           //     51,200

  const size_t fixed = szWb * 2 + szU * 2 + szH * 2 + szV + szXf + szXh * 2 + szY + szCnt;
  const bool pre = (ws_size >= fixed + 2 * szWa);

  char* p = (char*)d_ws;
  half_t *Wah = nullptr, *Wal = nullptr;
  if (pre) { Wah = (half_t*)p; p += szWa; Wal = (half_t*)p; p += szWa; }
  half_t* Wbh = (half_t*)p; p += szWb;
  half_t* Wbl = (half_t*)p; p += szWb;
  half_t* Uh  = (half_t*)p; p += szU;
  half_t* Ul  = (half_t*)p; p += szU;
  float*  HAg = (float*)p;  p += szH;
  float*  HBg = (float*)p;  p += szH;
  float*  Vg  = (float*)p;  p += szV;
  float*  Xf  = (float*)p;  p += szXf;
  half_t* Xh  = (half_t*)p; p += szXh;
  half_t* Xl  = (half_t*)p; p += szXh;
  float*  Yg  = (float*)p;  p += szY;
  unsigned* cnt = (unsigned*)p;

  // zero Y + cnt (contiguous) — harness re-poisons ws before every call
  {
    int nwords = (int)((szY + szCnt) / 4);
    k_zero<<<(nwords + 255) / 256, 256, 0, stream>>>((unsigned*)Yg, nwords);
  }
  k_hahb<<<NT * NB, NH, 0, stream>>>(ctx, W1a, b1a, W1b, b1b, HAg, HBg);
  k_v<<<NT * NB, NS, 0, stream>>>(b2b, us, Vg);
  k_permb<<<NS, 256, 0, stream>>>(W2b, Wbh, Wbl);
  k_u<<<NT, 256, 0, stream>>>(us, Uh, Ul);
  k_x0<<<NB, NS, 0, stream>>>(x0, Xf, Xh, Xl);
  if (pre) k_perma<<<NS, 256, 0, stream>>>(W2a, Wah, Wal);

  if (pre) {
    for (int t = 0; t < NT; ++t)
      k_step<true><<<2 * NS, 256, 0, stream>>>(t, W2a, b2a, Wah, Wal, Wbh, Wbl, Uh, Ul,
                                               HAg, HBg, Vg, Xf, Xh, Xl, Yg, cnt, out);
  } else {
    for (int t = 0; t < NT; ++t)
      k_step<false><<<2 * NS, 256, 0, stream>>>(t, W2a, b2a, Wah, Wal, Wbh, Wbl, Uh, Ul,
                                                HAg, HBg, Vg, Xf, Xh, Xl, Yg, cnt, out);
  }
}